// Round 1
// baseline (549.336 us; speedup 1.0000x reference)
//
#include <hip/hip_runtime.h>
#include <hip/hip_bf16.h>
#include <math.h>
#include <stdint.h>

#define BDIM 8192
#define DDIM 512
#define NT   64        // BDIM / 128
#define NPAIR 2080     // NT*(NT+1)/2
#define TEMP 10.0f

typedef __attribute__((ext_vector_type(8))) short bf16x8;
typedef __attribute__((ext_vector_type(4))) float f32x4;

__device__ __forceinline__ unsigned short f2bf(float f) {
  unsigned int x = __float_as_uint(f);
  x += 0x7fffu + ((x >> 16) & 1u);   // round-to-nearest-even
  return (unsigned short)(x >> 16);
}

__device__ __forceinline__ void red16(float& v) {
  v += __shfl_xor(v, 1);
  v += __shfl_xor(v, 2);
  v += __shfl_xor(v, 4);
  v += __shfl_xor(v, 8);
}

// ---------------- kernel 1: normalize rows, fold TEMP3 into u, store bf16 ----
__global__ __launch_bounds__(256) void knorm(const float* __restrict__ cnn,
                                             const float* __restrict__ rnn,
                                             unsigned short* __restrict__ u,
                                             unsigned short* __restrict__ v) {
  int wid = threadIdx.x >> 6, lane = threadIdx.x & 63;
  int gw = blockIdx.x * 4 + wid;          // 0 .. 2*BDIM-1
  const float* src;
  unsigned short* dst;
  int row;
  float mul;
  if (gw < BDIM) { src = cnn; dst = u; row = gw; mul = TEMP; }
  else           { src = rnn; dst = v; row = gw - BDIM; mul = 1.0f; }
  const float* p = src + (size_t)row * DDIM + lane * 8;
  float4 a0 = *(const float4*)p;
  float4 a1 = *(const float4*)(p + 4);
  float ss = a0.x*a0.x + a0.y*a0.y + a0.z*a0.z + a0.w*a0.w
           + a1.x*a1.x + a1.y*a1.y + a1.z*a1.z + a1.w*a1.w;
#pragma unroll
  for (int m = 1; m <= 32; m <<= 1) ss += __shfl_xor(ss, m);
  float inv = mul / sqrtf(ss);
  unsigned short o[8];
  o[0] = f2bf(a0.x * inv); o[1] = f2bf(a0.y * inv);
  o[2] = f2bf(a0.z * inv); o[3] = f2bf(a0.w * inv);
  o[4] = f2bf(a1.x * inv); o[5] = f2bf(a1.y * inv);
  o[6] = f2bf(a1.z * inv); o[7] = f2bf(a1.w * inv);
  *(uint4*)(dst + (size_t)row * DDIM + lane * 8) = *(uint4*)o;
}

// ---------------- kernel 2: fused GEMM-pair + masked online reductions -------
// ws acc layout: [NP, NN, ZN0, ZP0, SM0, ZN1, ZP1, SM1] each BDIM floats.
__global__ __launch_bounds__(512) void kmain(const unsigned short* __restrict__ u,
                                             const unsigned short* __restrict__ v,
                                             const float* __restrict__ idx,
                                             const float* __restrict__ probs,
                                             float* __restrict__ accb) {
  __shared__ float lds[128 * 129];
  const int tid = threadIdx.x, wid = tid >> 6, lane = tid & 63;
  const int l15 = lane & 15, lg = lane >> 4;

  // decode triangular pair index: blockIdx.x -> (ti, tj), ti <= tj
  int ti = 0, rem = blockIdx.x, rowlen = NT;
  while (rem >= rowlen) { rem -= rowlen; rowlen--; ti++; }
  const int tj = ti + rem;
  const bool diag = (ti == tj);
  const int I = ti * 128, J = tj * 128;

  const bool half0 = (wid < 4);           // waves 0-3: tile0 = S0[I,J]; 4-7: tile1 = S0[J,I]
  const int w4 = wid & 3, qr = w4 >> 1, qc = w4 & 1;
  const int R0 = (half0 ? I : J) + qr * 64;   // global A-row base (u rows)
  const int C0 = (half0 ? J : I) + qc * 64;   // global B-row base (v rows)

  f32x4 acc[4][4];
#pragma unroll
  for (int a = 0; a < 4; a++)
#pragma unroll
    for (int b = 0; b < 4; b++) acc[a][b] = (f32x4){0.f, 0.f, 0.f, 0.f};

  const unsigned short* Abase = u + (size_t)(R0 + l15) * DDIM + lg * 8;
  const unsigned short* Bbase = v + (size_t)(C0 + l15) * DDIM + lg * 8;
#pragma unroll 2
  for (int k0 = 0; k0 < DDIM; k0 += 32) {
    bf16x8 af[4], bfr[4];
#pragma unroll
    for (int ar = 0; ar < 4; ar++) af[ar] = *(const bf16x8*)(Abase + (size_t)ar * 16 * DDIM + k0);
#pragma unroll
    for (int bc = 0; bc < 4; bc++) bfr[bc] = *(const bf16x8*)(Bbase + (size_t)bc * 16 * DDIM + k0);
#pragma unroll
    for (int ar = 0; ar < 4; ar++)
#pragma unroll
      for (int bc = 0; bc < 4; bc++)
        acc[ar][bc] = __builtin_amdgcn_mfma_f32_16x16x32_bf16(af[ar], bfr[bc], acc[ar][bc], 0, 0, 0);
  }

  float* NP  = accb + 0 * BDIM;
  float* NN  = accb + 1 * BDIM;
  float* ZN0 = accb + 2 * BDIM;
  float* ZP0 = accb + 3 * BDIM;
  float* SM0 = accb + 4 * BDIM;
  float* ZN1 = accb + 5 * BDIM;
  float* ZP1 = accb + 6 * BDIM;
  float* SM1 = accb + 7 * BDIM;
  const float th1 = probs[0], th2 = probs[1];

  // Phase A: waves 0-3 stash tile0 in LDS (row-major, pad 129 -> conflict-free transpose reads)
  if (half0) {
#pragma unroll
    for (int ar = 0; ar < 4; ar++)
#pragma unroll
      for (int bc = 0; bc < 4; bc++) {
        int Rb = qr * 64 + ar * 16 + lg * 4;
        int C  = qc * 64 + bc * 16 + l15;
#pragma unroll
        for (int j = 0; j < 4; j++) lds[(Rb + j) * 129 + C] = acc[ar][bc][j];
      }
  }
  __syncthreads();

  // Phase B
  if (half0) {
    // update (a): loss0 rows I, mask idx[I+R, J+C], with counts
#pragma unroll 1
    for (int ar = 0; ar < 4; ar++)
#pragma unroll 1
      for (int j = 0; j < 4; j++) {
        int R = qr * 64 + ar * 16 + lg * 4 + j;
        float zn = 0, zp = 0, sm = 0, cn = 0, cp = 0;
#pragma unroll
        for (int bc = 0; bc < 4; bc++) {
          int C = qc * 64 + bc * 16 + l15;
          float x = idx[(size_t)(I + R) * BDIM + (J + C)];
          float s = acc[ar][bc][j];
          float e = __expf(s - TEMP);
          if (x <= th2) { zn += e; cn += 1.f; }
          if (x >  th1) { zp += e; sm += s; cp += 1.f; }
        }
        red16(zn); red16(zp); red16(sm); red16(cn); red16(cp);
        if (l15 == 0) {
          int r = I + R;
          atomicAdd(&ZN0[r], zn); atomicAdd(&ZP0[r], zp); atomicAdd(&SM0[r], sm);
          atomicAdd(&NN[r], cn);  atomicAdd(&NP[r], cp);
        }
      }
  } else if (!diag) {
    // updates (b)+(d): loss0 rows J (own tile1 regs) and loss1 rows J (tile0^T via LDS),
    // both masked by the same idx[J+R, I+C]
#pragma unroll 1
    for (int ar = 0; ar < 4; ar++)
#pragma unroll 1
      for (int j = 0; j < 4; j++) {
        int R = qr * 64 + ar * 16 + lg * 4 + j;
        float zn0 = 0, zp0 = 0, sm0 = 0, zn1 = 0, zp1 = 0, sm1 = 0, cn = 0, cp = 0;
#pragma unroll
        for (int bc = 0; bc < 4; bc++) {
          int C = qc * 64 + bc * 16 + l15;
          float x  = idx[(size_t)(J + R) * BDIM + (I + C)];
          float s0 = acc[ar][bc][j];        // S0[J+R, I+C]
          float s1 = lds[C * 129 + R];      // tile0[C][R] = S0[I+C, J+R] = S1[J+R, I+C]
          float e0 = __expf(s0 - TEMP), e1 = __expf(s1 - TEMP);
          if (x <= th2) { zn0 += e0; zn1 += e1; cn += 1.f; }
          if (x >  th1) { zp0 += e0; sm0 += s0; zp1 += e1; sm1 += s1; cp += 1.f; }
        }
        red16(zn0); red16(zp0); red16(sm0); red16(zn1); red16(zp1); red16(sm1); red16(cn); red16(cp);
        if (l15 == 0) {
          int r = J + R;
          atomicAdd(&ZN0[r], zn0); atomicAdd(&ZP0[r], zp0); atomicAdd(&SM0[r], sm0);
          atomicAdd(&ZN1[r], zn1); atomicAdd(&ZP1[r], zp1); atomicAdd(&SM1[r], sm1);
          atomicAdd(&NN[r], cn);   atomicAdd(&NP[r], cp);
        }
      }
  }
  __syncthreads();

  // Phase C: waves 4-7 stash tile1 in LDS (for diag this rewrites identical values)
  if (!half0) {
#pragma unroll
    for (int ar = 0; ar < 4; ar++)
#pragma unroll
      for (int bc = 0; bc < 4; bc++) {
        int Rb = qr * 64 + ar * 16 + lg * 4;
        int C  = qc * 64 + bc * 16 + l15;
#pragma unroll
        for (int j = 0; j < 4; j++) lds[(Rb + j) * 129 + C] = acc[ar][bc][j];
      }
  }
  __syncthreads();

  // Phase D: waves 0-3, update (c): loss1 rows I from tile1^T, mask idx[I+R, J+C]
  if (half0) {
#pragma unroll 1
    for (int ar = 0; ar < 4; ar++)
#pragma unroll 1
      for (int j = 0; j < 4; j++) {
        int R = qr * 64 + ar * 16 + lg * 4 + j;
        float zn1 = 0, zp1 = 0, sm1 = 0;
#pragma unroll
        for (int bc = 0; bc < 4; bc++) {
          int C = qc * 64 + bc * 16 + l15;
          float x  = idx[(size_t)(I + R) * BDIM + (J + C)];
          float s1 = lds[C * 129 + R];      // tile1[C][R] = S0[J+C, I+R] = S1[I+R, J+C]
          float e1 = __expf(s1 - TEMP);
          if (x <= th2) zn1 += e1;
          if (x >  th1) { zp1 += e1; sm1 += s1; }
        }
        red16(zn1); red16(zp1); red16(sm1);
        if (l15 == 0) {
          int r = I + R;
          atomicAdd(&ZN1[r], zn1); atomicAdd(&ZP1[r], zp1); atomicAdd(&SM1[r], sm1);
        }
      }
  }
}

// ---------------- kernel 3: per-row loss terms + scalar reduction ------------
__global__ __launch_bounds__(1024) void kfinal(const float* __restrict__ accb,
                                               float* __restrict__ out) {
  float tot = 0.f;
  for (int i = threadIdx.x; i < BDIM; i += 1024) {
    float np  = accb[i];
    float nn  = accb[BDIM + i];
    float zn0 = accb[2 * BDIM + i], zp0 = accb[3 * BDIM + i], sm0 = accb[4 * BDIM + i];
    float zn1 = accb[5 * BDIM + i], zp1 = accb[6 * BDIM + i], sm1 = accb[7 * BDIM + i];
    float inv = 1.f / (np * (1.f + nn));
    // sum_{pos} log(1+e^{lse-s}) = np*lse - sum_pos(s) + Zp/Zn  (2nd order ~1e-11)
    float l0 = (np * (TEMP + logf(zn0)) - sm0 + zp0 / zn0) * inv;
    float l1 = (np * (TEMP + logf(zn1)) - sm1 + zp1 / zn1) * inv;
    tot += l0 + l1;
  }
#pragma unroll
  for (int m = 1; m <= 32; m <<= 1) tot += __shfl_xor(tot, m);
  __shared__ float sred[16];
  int wid = threadIdx.x >> 6, lane = threadIdx.x & 63;
  if (lane == 0) sred[wid] = tot;
  __syncthreads();
  if (threadIdx.x == 0) {
    float s = 0.f;
    for (int k = 0; k < 16; k++) s += sred[k];
    out[0] = s / (float)BDIM;
  }
}

extern "C" void kernel_launch(void* const* d_in, const int* in_sizes, int n_in,
                              void* d_out, int out_size, void* d_ws, size_t ws_size,
                              hipStream_t stream) {
  (void)in_sizes; (void)n_in; (void)out_size; (void)ws_size;
  const float* cnn   = (const float*)d_in[0];
  const float* rnn   = (const float*)d_in[1];
  const float* idx   = (const float*)d_in[2];
  const float* probs = (const float*)d_in[3];
  char* w = (char*)d_ws;
  unsigned short* u = (unsigned short*)w;                                  // 8 MB
  unsigned short* v = (unsigned short*)(w + (size_t)BDIM * DDIM * 2);      // 8 MB
  float* accb = (float*)(w + (size_t)BDIM * DDIM * 4);                     // 256 KB

  hipMemsetAsync(accb, 0, 8 * BDIM * sizeof(float), stream);
  knorm<<<(2 * BDIM) / 4, 256, 0, stream>>>(cnn, rnn, u, v);
  kmain<<<NPAIR, 512, 0, stream>>>(u, v, idx, probs, accb);
  kfinal<<<1, 1024, 0, stream>>>(accb, (float*)d_out);
}

// Round 2
// 431.788 us; speedup vs baseline: 1.2722x; 1.2722x over previous
//
#include <hip/hip_runtime.h>
#include <hip/hip_bf16.h>
#include <math.h>
#include <stdint.h>

#define BDIM 8192
#define DDIM 512
#define NT   64        // BDIM / 128
#define TEMP 10.0f

typedef __attribute__((ext_vector_type(8))) short bf16x8;
typedef __attribute__((ext_vector_type(4))) float f32x4;

__device__ __forceinline__ unsigned short f2bf(float f) {
  unsigned int x = __float_as_uint(f);
  x += 0x7fffu + ((x >> 16) & 1u);   // round-to-nearest-even
  return (unsigned short)(x >> 16);
}

__device__ __forceinline__ void red16(float& v) {
  v += __shfl_xor(v, 1);
  v += __shfl_xor(v, 2);
  v += __shfl_xor(v, 4);
  v += __shfl_xor(v, 8);
}

// ---------------- kernel 1: normalize rows, fold TEMP3 into u, store bf16 ----
__global__ __launch_bounds__(256) void knorm(const float* __restrict__ cnn,
                                             const float* __restrict__ rnn,
                                             unsigned short* __restrict__ u,
                                             unsigned short* __restrict__ v) {
  int wid = threadIdx.x >> 6, lane = threadIdx.x & 63;
  int gw = blockIdx.x * 4 + wid;          // 0 .. 2*BDIM-1
  const float* src;
  unsigned short* dst;
  int row;
  float mul;
  if (gw < BDIM) { src = cnn; dst = u; row = gw; mul = TEMP; }
  else           { src = rnn; dst = v; row = gw - BDIM; mul = 1.0f; }
  const float* p = src + (size_t)row * DDIM + lane * 8;
  float4 a0 = *(const float4*)p;
  float4 a1 = *(const float4*)(p + 4);
  float ss = a0.x*a0.x + a0.y*a0.y + a0.z*a0.z + a0.w*a0.w
           + a1.x*a1.x + a1.y*a1.y + a1.z*a1.z + a1.w*a1.w;
#pragma unroll
  for (int m = 1; m <= 32; m <<= 1) ss += __shfl_xor(ss, m);
  float inv = mul / sqrtf(ss);
  unsigned short o[8];
  o[0] = f2bf(a0.x * inv); o[1] = f2bf(a0.y * inv);
  o[2] = f2bf(a0.z * inv); o[3] = f2bf(a0.w * inv);
  o[4] = f2bf(a1.x * inv); o[5] = f2bf(a1.y * inv);
  o[6] = f2bf(a1.z * inv); o[7] = f2bf(a1.w * inv);
  *(uint4*)(dst + (size_t)row * DDIM + lane * 8) = *(uint4*)o;
}

// ---------------- kernel 2: tile GEMM (normal + swapped) + masked reductions --
// One 128x128 tile per WG (4 waves, 2x2 quadrants of 64x64).
// acc  = S0[I-block, J-block]            -> loss0 stats for rows I  (mask idx(I,J), coalesced)
// accT = transpose (swapped-operand mfma) -> loss1 stats for rows J  (mask idx(J,I), coalesced)
// Partials: LDS pre-reduce, then plain coalesced stores into private slot of
// P[64 slot][8 stat][8192 row]  (loss0 slot=tj, loss1 slot=ti). No global atomics.
__global__ __launch_bounds__(256, 2) void kmain(const unsigned short* __restrict__ u,
                                                const unsigned short* __restrict__ v,
                                                const float* __restrict__ idx,
                                                const float* __restrict__ probs,
                                                float* __restrict__ P) {
  __shared__ float L0[5 * 128];
  __shared__ float L1[3 * 128];
  const int tid = threadIdx.x, lane = tid & 63, wid = tid >> 6;
  const int l15 = lane & 15, lg = lane >> 4;
  const int qr = wid >> 1, qc = wid & 1;

  for (int t = tid; t < 1024; t += 256) {
    if (t < 640) L0[t] = 0.f; else L1[t - 640] = 0.f;
  }

  // blockIdx remap: pair (ti,tj)/(tj,ti) differ by 8 in bid -> same XCD slot,
  // co-resident -> each idx tile's two reads share L2.
  int bid = blockIdx.x;
  int g = bid >> 4, r16 = bid & 15;
  int p = g * 8 + (r16 & 7), orient = r16 >> 3;
  int ti, tj;
  if (p < 2016) {                       // off-diagonal pair (a < b)
    int a = 0, rem = p, rowlen = 63;
    while (rem >= rowlen) { rem -= rowlen; rowlen--; a++; }
    int b = a + 1 + rem;
    ti = orient ? b : a; tj = orient ? a : b;
  } else {                              // 32 leftover slots x 2 orients = 64 diagonals
    int d = (p - 2016) * 2 + orient;
    ti = d; tj = d;
  }
  const int I = ti * 128, J = tj * 128;

  f32x4 acc[4][4], accT[4][4];
#pragma unroll
  for (int a = 0; a < 4; a++)
#pragma unroll
    for (int b = 0; b < 4; b++) { acc[a][b] = (f32x4){0,0,0,0}; accT[a][b] = (f32x4){0,0,0,0}; }

  const unsigned short* Abase = u + (size_t)(I + qr * 64 + l15) * DDIM + lg * 8;
  const unsigned short* Bbase = v + (size_t)(J + qc * 64 + l15) * DDIM + lg * 8;
#pragma unroll 2
  for (int k0 = 0; k0 < DDIM; k0 += 32) {
    bf16x8 af[4], bf_[4];
#pragma unroll
    for (int ar = 0; ar < 4; ar++) af[ar] = *(const bf16x8*)(Abase + (size_t)ar * 16 * DDIM + k0);
#pragma unroll
    for (int bc = 0; bc < 4; bc++) bf_[bc] = *(const bf16x8*)(Bbase + (size_t)bc * 16 * DDIM + k0);
#pragma unroll
    for (int ar = 0; ar < 4; ar++)
#pragma unroll
      for (int bc = 0; bc < 4; bc++) {
        acc[ar][bc]  = __builtin_amdgcn_mfma_f32_16x16x32_bf16(af[ar], bf_[bc], acc[ar][bc], 0, 0, 0);
        accT[bc][ar] = __builtin_amdgcn_mfma_f32_16x16x32_bf16(bf_[bc], af[ar], accT[bc][ar], 0, 0, 0);
      }
  }

  const float th1 = probs[0], th2 = probs[1];
  __syncthreads();   // LDS zeroing visible before atomics

  // ---- loss0: rows I+R, reduce over columns; mask idx[I+R, J+C] (coalesced) ----
#pragma unroll
  for (int ar = 0; ar < 4; ar++) {
#pragma unroll
    for (int j = 0; j < 4; j++) {
      int R = qr * 64 + ar * 16 + lg * 4 + j;
      const float* row = idx + (size_t)(I + R) * BDIM + J + qc * 64 + l15;
      float zn = 0, zp = 0, sm = 0, cn = 0, cp = 0;
#pragma unroll
      for (int bc = 0; bc < 4; bc++) {
        float x = row[bc * 16];
        float s = acc[ar][bc][j];
        float e = __expf(s - TEMP);
        if (x <= th2) { zn += e; cn += 1.f; }
        if (x >  th1) { zp += e; sm += s; cp += 1.f; }
      }
      red16(zn); red16(zp); red16(sm); red16(cn); red16(cp);
      if (l15 == 0) {
        atomicAdd(&L0[0 * 128 + R], cp);
        atomicAdd(&L0[1 * 128 + R], cn);
        atomicAdd(&L0[2 * 128 + R], zn);
        atomicAdd(&L0[3 * 128 + R], zp);
        atomicAdd(&L0[4 * 128 + R], sm);
      }
    }
  }

  // ---- loss1: rows J+C, reduce over I-cols; mask idx[J+C, I+R] (coalesced) ----
#pragma unroll
  for (int bc = 0; bc < 4; bc++) {
#pragma unroll
    for (int j = 0; j < 4; j++) {
      int C = qc * 64 + bc * 16 + lg * 4 + j;
      const float* rowT = idx + (size_t)(J + C) * BDIM + I + qr * 64 + l15;
      float zn = 0, zp = 0, sm = 0;
#pragma unroll
      for (int ar = 0; ar < 4; ar++) {
        float x = rowT[ar * 16];
        float s = accT[bc][ar][j];
        float e = __expf(s - TEMP);
        if (x <= th2) zn += e;
        if (x >  th1) { zp += e; sm += s; }
      }
      red16(zn); red16(zp); red16(sm);
      if (l15 == 0) {
        atomicAdd(&L1[0 * 128 + C], zn);
        atomicAdd(&L1[1 * 128 + C], zp);
        atomicAdd(&L1[2 * 128 + C], sm);
      }
    }
  }
  __syncthreads();

  // ---- write private slot (plain coalesced stores, every cell written once) ----
  for (int t = tid; t < 1024; t += 256) {
    int s = t >> 7, c = t & 127;
    if (s < 5) P[((size_t)tj * 8 + s) * BDIM + I + c] = L0[s * 128 + c];
    else       P[((size_t)ti * 8 + s) * BDIM + J + c] = L1[(s - 5) * 128 + c];
  }
}

// ---------------- kernel 3: reduce slots, per-row loss, block partials --------
__global__ __launch_bounds__(128) void kfinal(const float* __restrict__ P,
                                              float* __restrict__ part) {
  int r = blockIdx.x * 128 + threadIdx.x;
  float st[8] = {0, 0, 0, 0, 0, 0, 0, 0};
  for (int k = 0; k < 64; k++) {
#pragma unroll
    for (int s = 0; s < 8; s++) st[s] += P[((size_t)k * 8 + s) * BDIM + r];
  }
  float np = st[0], nn = st[1];
  float inv = 1.f / (np * (1.f + nn));
  // sum_{pos} log(1+e^{lse-s}) = np*lse - sum_pos(s) + Zp/Zn  (2nd order ~1e-11)
  float l0 = (np * (TEMP + logf(st[2])) - st[4] + st[3] / st[2]) * inv;
  float l1 = (np * (TEMP + logf(st[5])) - st[7] + st[6] / st[5]) * inv;
  float tot = l0 + l1;
#pragma unroll
  for (int m = 1; m <= 32; m <<= 1) tot += __shfl_xor(tot, m);
  __shared__ float sb;
  if (threadIdx.x == 0) sb = tot;
  __syncthreads();
  if (threadIdx.x == 64) part[blockIdx.x] = sb + tot;
}

__global__ __launch_bounds__(64) void kfinal2(const float* __restrict__ part,
                                              float* __restrict__ out) {
  float t = part[threadIdx.x];
#pragma unroll
  for (int m = 1; m <= 32; m <<= 1) t += __shfl_xor(t, m);
  if (threadIdx.x == 0) out[0] = t / (float)BDIM;
}

extern "C" void kernel_launch(void* const* d_in, const int* in_sizes, int n_in,
                              void* d_out, int out_size, void* d_ws, size_t ws_size,
                              hipStream_t stream) {
  (void)in_sizes; (void)n_in; (void)out_size; (void)ws_size;
  const float* cnn   = (const float*)d_in[0];
  const float* rnn   = (const float*)d_in[1];
  const float* idx   = (const float*)d_in[2];
  const float* probs = (const float*)d_in[3];
  char* w = (char*)d_ws;
  unsigned short* u = (unsigned short*)w;                                  // 8 MB
  unsigned short* v = (unsigned short*)(w + (size_t)BDIM * DDIM * 2);      // 8 MB
  float* P    = (float*)(w + (size_t)BDIM * DDIM * 4);                     // 16 MB
  float* part = (float*)(w + (size_t)BDIM * DDIM * 4 + (size_t)NT * 8 * BDIM * 4);

  knorm<<<(2 * BDIM) / 4, 256, 0, stream>>>(cnn, rnn, u, v);
  kmain<<<NT * NT, 256, 0, stream>>>(u, v, idx, probs, P);
  kfinal<<<BDIM / 128, 128, 0, stream>>>(P, part);
  kfinal2<<<1, 64, 0, stream>>>(part, (float*)d_out);
}